// Round 13
// baseline (1683.863 us; speedup 1.0000x reference)
//
#include <hip/hip_runtime.h>

#define NN 100000
#define NE 1600000
#define NG 64

typedef __attribute__((ext_vector_type(8))) short bf16x8;
typedef __attribute__((ext_vector_type(4))) float f32x4;

__device__ __forceinline__ unsigned short f2bf(float f) {
  unsigned u = __float_as_uint(f);
  unsigned r = u + 0x7FFFu + ((u >> 16) & 1u);
  return (unsigned short)(r >> 16);
}
__device__ __forceinline__ float bf2f(unsigned u16) {
  return __uint_as_float(u16 << 16);
}

__device__ __forceinline__ float wave_sum(float v) {
#pragma unroll
  for (int off = 32; off; off >>= 1) v += __shfl_down(v, off, 64);
  return v;
}
__device__ __forceinline__ float wave_max(float v) {
#pragma unroll
  for (int off = 32; off; off >>= 1) v = fmaxf(v, __shfl_down(v, off, 64));
  return v;
}

__device__ __forceinline__ float sigm(float v) { return 1.f / (1.f + __expf(-v)); }

// ---------------- gather: one wave per (etype,node) task, row-layout S ----------------
__global__ void __launch_bounds__(256)
gather_k(const unsigned* __restrict__ hbf32, const int* __restrict__ rowst,
         const int* __restrict__ payload, unsigned short* __restrict__ S) {
  const int lane = threadIdx.x & 63, wid = threadIdx.x >> 6;
  int task = blockIdx.x * 4 + wid;
  if (task >= 3 * NN) return;
  const int s = rowst[task], e = rowst[task + 1];
  float sx = 0.f, sy = 0.f;
  int i = s;
  for (; i + 4 <= e; i += 4) {
    int p0 = payload[i], p1 = payload[i + 1], p2 = payload[i + 2], p3 = payload[i + 3];
    unsigned v0 = hbf32[(size_t)p0 * 64 + lane];
    unsigned v1 = hbf32[(size_t)p1 * 64 + lane];
    unsigned v2 = hbf32[(size_t)p2 * 64 + lane];
    unsigned v3 = hbf32[(size_t)p3 * 64 + lane];
    sx += bf2f(v0 & 0xffffu) + bf2f(v1 & 0xffffu) + bf2f(v2 & 0xffffu) + bf2f(v3 & 0xffffu);
    sy += bf2f(v0 >> 16) + bf2f(v1 >> 16) + bf2f(v2 >> 16) + bf2f(v3 >> 16);
  }
  const int rem = e - i;
  if (rem == 3) {
    int p0 = payload[i], p1 = payload[i + 1], p2 = payload[i + 2];
    unsigned v0 = hbf32[(size_t)p0 * 64 + lane];
    unsigned v1 = hbf32[(size_t)p1 * 64 + lane];
    unsigned v2 = hbf32[(size_t)p2 * 64 + lane];
    sx += bf2f(v0 & 0xffffu) + bf2f(v1 & 0xffffu) + bf2f(v2 & 0xffffu);
    sy += bf2f(v0 >> 16) + bf2f(v1 >> 16) + bf2f(v2 >> 16);
  } else if (rem == 2) {
    int p0 = payload[i], p1 = payload[i + 1];
    unsigned v0 = hbf32[(size_t)p0 * 64 + lane];
    unsigned v1 = hbf32[(size_t)p1 * 64 + lane];
    sx += bf2f(v0 & 0xffffu) + bf2f(v1 & 0xffffu);
    sy += bf2f(v0 >> 16) + bf2f(v1 >> 16);
  } else if (rem == 1) {
    int p0 = payload[i];
    unsigned v0 = hbf32[(size_t)p0 * 64 + lane];
    sx += bf2f(v0 & 0xffffu);
    sy += bf2f(v0 >> 16);
  }
  const int et = task / NN;
  const int n = task - et * NN;
  unsigned pk = (unsigned)f2bf(sx) | ((unsigned)f2bf(sy) << 16);
  *(unsigned*)(S + (size_t)n * 384 + et * 128 + 2 * lane) = pk;
}

// ---------------- fragment-major packs ----------------
// K=128, 3 gate panels: fidx = ((g*4+ks)*8 + cc)*64 + lane
__global__ void pack_fragB(const float* __restrict__ W, unsigned short* __restrict__ WF) {
  int idx = blockIdx.x * 256 + threadIdx.x;
  if (idx >= 3 * 4 * 8 * 64) return;
  int lane = idx & 63;
  int cc = (idx >> 6) & 7;
  int ks = (idx >> 9) & 3;
  int g = idx >> 11;
  int col = cc * 16 + (lane & 15);
  int k0 = ks * 32 + (lane >> 4) * 8;
  const float* src = W + ((size_t)g * 128 + col) * 128 + k0;
  bf16x8 o;
#pragma unroll
  for (int j = 0; j < 8; ++j) o[j] = (short)f2bf(src[j]);
  *(bf16x8*)(WF + (size_t)idx * 8) = o;
}

// K=256 stacked [Wih;Whh] for gates r(g=0), z(g=1): fidx = ((g*8+ks)*8 + cc)*64 + lane
__global__ void pack_rz(const float* __restrict__ Wih, const float* __restrict__ Whh,
                        unsigned short* __restrict__ WF) {
  int idx = blockIdx.x * 256 + threadIdx.x;
  if (idx >= 2 * 8 * 8 * 64) return;
  int lane = idx & 63;
  int cc = (idx >> 6) & 7;
  int ks = (idx >> 9) & 7;
  int g = idx >> 12;
  int col = cc * 16 + (lane & 15);
  int k0 = ks * 32 + (lane >> 4) * 8;
  int row = g * 128 + col;
  const float* src = (k0 < 128) ? (Wih + (size_t)row * 128 + k0)
                                : (Whh + (size_t)row * 128 + (k0 - 128));
  bf16x8 o;
#pragma unroll
  for (int j = 0; j < 8; ++j) o[j] = (short)f2bf(src[j]);
  *(bf16x8*)(WF + (size_t)idx * 8) = o;
}

// K=384 pack of Wmsg as B[k=et*128+h][col=d] = Wmsg[et,d,h]
__global__ void pack_cat384(const float* __restrict__ Wmsg, unsigned short* __restrict__ WF) {
  int idx = blockIdx.x * 256 + threadIdx.x;
  if (idx >= 12 * 8 * 64) return;
  int lane = idx & 63;
  int cc = (idx >> 6) & 7;
  int ks = idx >> 9;
  int col = cc * 16 + (lane & 15);
  int k0 = ks * 32 + (lane >> 4) * 8;
  int et = k0 >> 7, h0 = k0 & 127;
  const float* src = Wmsg + (size_t)et * 16384 + (size_t)col * 128 + h0;
  bf16x8 o;
#pragma unroll
  for (int j = 0; j < 8; ++j) o[j] = (short)f2bf(src[j]);
  *(bf16x8*)(WF + (size_t)idx * 8) = o;
}

// ---------------- msg GEMM: a = S @ Wcat^T + deg bias (K=384), coalesced store ----------------
__global__ void __launch_bounds__(256)
msg_gemm6(const unsigned short* __restrict__ S, const unsigned short* __restrict__ WcatF,
          const float* __restrict__ bmsg, const int* __restrict__ rowst,
          unsigned short* __restrict__ abf) {
  __shared__ char Ss[49152];  // 64 rows x 384 bf16 (768B), swizzled; first 16KB reused for out
  const int tid = threadIdx.x, lane = tid & 63, wid = tid >> 6;
  const int l15 = lane & 15, lhi = lane >> 4;
  const int bm = blockIdx.x * 64;
  const int wrow0 = (wid >> 1) * 32, wcol0 = (wid & 1) * 64;

  for (int idx = tid; idx < 3072; idx += 256) {
    int row = idx / 48, o = (idx - row * 48) * 16;
    int gr = bm + row;
    uint4 v = make_uint4(0, 0, 0, 0);
    if (gr < NN) v = *(const uint4*)((const char*)S + (size_t)gr * 768 + o);
    *(uint4*)(Ss + row * 768 + (o ^ ((row & 7) << 4))) = v;
  }
  __syncthreads();

  f32x4 acc[8];
#pragma unroll
  for (int f = 0; f < 8; ++f)
#pragma unroll
    for (int r = 0; r < 4; ++r) acc[f][r] = 0.f;

#pragma unroll
  for (int ks = 0; ks < 12; ++ks) {
    int kb = ks * 64 + lhi * 16;
    bf16x8 fS[2];
#pragma unroll
    for (int mf = 0; mf < 2; ++mf) {
      int row = wrow0 + mf * 16 + l15;
      fS[mf] = *(const bf16x8*)(Ss + row * 768 + (kb ^ ((row & 7) << 4)));
    }
#pragma unroll
    for (int nf = 0; nf < 4; ++nf) {
      bf16x8 bw = *(const bf16x8*)(WcatF +
          (((size_t)ks * 8 + (wcol0 >> 4) + nf) * 64 + lane) * 8);
#pragma unroll
      for (int mf = 0; mf < 2; ++mf)
        acc[mf * 4 + nf] = __builtin_amdgcn_mfma_f32_16x16x32_bf16(
            fS[mf], bw, acc[mf * 4 + nf], 0, 0, 0);
    }
  }
  __syncthreads();  // everyone done reading Ss; reuse first 16KB for output tile

  // stage bias-applied a-tile into LDS (swizzled), then coalesced store
#pragma unroll
  for (int mf = 0; mf < 2; ++mf)
#pragma unroll
    for (int r = 0; r < 4; ++r) {
      int m = wrow0 + mf * 16 + lhi * 4 + r;
      int grow = bm + m;
      float d0 = 0.f, d1 = 0.f, d2 = 0.f;
      if (grow < NN) {
        d0 = (float)(rowst[grow + 1] - rowst[grow]);
        d1 = (float)(rowst[NN + grow + 1] - rowst[NN + grow]);
        d2 = (float)(rowst[2 * NN + grow + 1] - rowst[2 * NN + grow]);
      }
      int sw = (m & 7) << 4;
#pragma unroll
      for (int nf = 0; nf < 4; ++nf) {
        int col = wcol0 + nf * 16 + l15;
        float v = acc[mf * 4 + nf][r] + d0 * bmsg[col] + d1 * bmsg[128 + col] +
                  d2 * bmsg[256 + col];
        *(unsigned short*)(Ss + m * 256 + ((2 * col) ^ sw)) = f2bf(v);
      }
    }
  __syncthreads();
  for (int idx = tid; idx < 1024; idx += 256) {
    int row = idx >> 4, seg = idx & 15;
    int gr = bm + row;
    if (gr < NN) {
      uint4 v = *(const uint4*)(Ss + row * 256 + ((seg * 16) ^ ((row & 7) << 4)));
      *(uint4*)((char*)abf + (size_t)gr * 256 + seg * 16) = v;
    }
  }
}

// ---------------- GRU v5: hi/lo h, r->n->z, coalesced hi/lo store via LDS ----------------
__global__ void __launch_bounds__(256, 3)
gru5(unsigned short* __restrict__ hbf, unsigned short* __restrict__ hlo,
     const unsigned short* __restrict__ abf, const unsigned short* __restrict__ WrzF,
     const unsigned short* __restrict__ WihF, const unsigned short* __restrict__ WhhF,
     const float* __restrict__ bih, const float* __restrict__ bhh) {
  __shared__ char cat[64 * 512];  // per row: [a 256B | h 256B], swizzled within row
  const int tid = threadIdx.x, lane = tid & 63, wid = tid >> 6;
  const int l15 = lane & 15, lhi = lane >> 4;
  const int bm = blockIdx.x * 64;
  const int wrow0 = (wid >> 1) * 32, wcol0 = (wid & 1) * 64;

  for (int idx = tid; idx < 2048; idx += 256) {
    int row = idx >> 5, seg = idx & 31;
    int gr = bm + row;
    uint4 v = make_uint4(0, 0, 0, 0);
    if (gr < NN) {
      if (seg < 16)
        v = *(const uint4*)((const char*)abf + (size_t)gr * 256 + seg * 16);
      else
        v = *(const uint4*)((const char*)hbf + (size_t)gr * 256 + (seg - 16) * 16);
    }
    int o = seg * 16;
    *(uint4*)(cat + row * 512 + (o ^ ((row & 7) << 4))) = v;
  }
  __syncthreads();

  // ---- gate r: K=256 concat ----
  f32x4 rr[8];
  {
    f32x4 acc[8];
#pragma unroll
    for (int f = 0; f < 8; ++f)
#pragma unroll
      for (int r = 0; r < 4; ++r) acc[f][r] = 0.f;
#pragma unroll
    for (int ks = 0; ks < 8; ++ks) {
      int kb = ks * 64 + lhi * 16;
      bf16x8 fA[2];
#pragma unroll
      for (int mf = 0; mf < 2; ++mf) {
        int row = wrow0 + mf * 16 + l15;
        fA[mf] = *(const bf16x8*)(cat + row * 512 + (kb ^ ((row & 7) << 4)));
      }
#pragma unroll
      for (int nf = 0; nf < 4; ++nf) {
        bf16x8 bw = *(const bf16x8*)(WrzF +
            (((size_t)ks * 8 + (wcol0 >> 4) + nf) * 64 + lane) * 8);
#pragma unroll
        for (int mf = 0; mf < 2; ++mf)
          acc[mf * 4 + nf] = __builtin_amdgcn_mfma_f32_16x16x32_bf16(
              fA[mf], bw, acc[mf * 4 + nf], 0, 0, 0);
      }
    }
#pragma unroll
    for (int f = 0; f < 8; ++f) {
      int col = wcol0 + ((f & 3) * 16) + l15;
      float b = bih[col] + bhh[col];
#pragma unroll
      for (int r = 0; r < 4; ++r) rr[f][r] = sigm(acc[f][r] + b);
    }
  }

  // ---- gate n: separate acc_i (a half) and acc_h (h half) ----
  f32x4 nn[8];
  {
    f32x4 acc_i[8], acc_h[8];
#pragma unroll
    for (int f = 0; f < 8; ++f)
#pragma unroll
      for (int r = 0; r < 4; ++r) { acc_i[f][r] = 0.f; acc_h[f][r] = 0.f; }
#pragma unroll
    for (int ks = 0; ks < 4; ++ks) {
      int kb = ks * 64 + lhi * 16;
      bf16x8 fa[2], fh[2];
#pragma unroll
      for (int mf = 0; mf < 2; ++mf) {
        int row = wrow0 + mf * 16 + l15;
        int sw = (row & 7) << 4;
        fa[mf] = *(const bf16x8*)(cat + row * 512 + (kb ^ sw));
        fh[mf] = *(const bf16x8*)(cat + row * 512 + ((256 + kb) ^ sw));
      }
#pragma unroll
      for (int nf = 0; nf < 4; ++nf) {
        size_t fidx = (((size_t)(2 * 4 + ks) * 8 + (wcol0 >> 4) + nf) * 64 + lane) * 8;
        bf16x8 bi = *(const bf16x8*)(WihF + fidx);
        bf16x8 bh = *(const bf16x8*)(WhhF + fidx);
#pragma unroll
        for (int mf = 0; mf < 2; ++mf) {
          int f = mf * 4 + nf;
          acc_i[f] = __builtin_amdgcn_mfma_f32_16x16x32_bf16(fa[mf], bi, acc_i[f], 0, 0, 0);
          acc_h[f] = __builtin_amdgcn_mfma_f32_16x16x32_bf16(fh[mf], bh, acc_h[f], 0, 0, 0);
        }
      }
    }
#pragma unroll
    for (int f = 0; f < 8; ++f) {
      int col = wcol0 + ((f & 3) * 16) + l15;
      float bi = bih[256 + col], bh = bhh[256 + col];
#pragma unroll
      for (int r = 0; r < 4; ++r) {
        float x = acc_i[f][r] + bi + rr[f][r] * (acc_h[f][r] + bh);
        float e = __expf(-2.f * x);
        nn[f][r] = (1.f - e) / (1.f + e);
      }
    }
  }

  // ---- gate z: K=256 concat, blend into registers ----
  f32x4 hv[8];
  {
    f32x4 acc[8];
#pragma unroll
    for (int f = 0; f < 8; ++f)
#pragma unroll
      for (int r = 0; r < 4; ++r) acc[f][r] = 0.f;
#pragma unroll
    for (int ks = 0; ks < 8; ++ks) {
      int kb = ks * 64 + lhi * 16;
      bf16x8 fA[2];
#pragma unroll
      for (int mf = 0; mf < 2; ++mf) {
        int row = wrow0 + mf * 16 + l15;
        fA[mf] = *(const bf16x8*)(cat + row * 512 + (kb ^ ((row & 7) << 4)));
      }
#pragma unroll
      for (int nf = 0; nf < 4; ++nf) {
        bf16x8 bw = *(const bf16x8*)(WrzF +
            (((size_t)(8 + ks) * 8 + (wcol0 >> 4) + nf) * 64 + lane) * 8);
#pragma unroll
        for (int mf = 0; mf < 2; ++mf)
          acc[mf * 4 + nf] = __builtin_amdgcn_mfma_f32_16x16x32_bf16(
              fA[mf], bw, acc[mf * 4 + nf], 0, 0, 0);
      }
    }
#pragma unroll
    for (int mf = 0; mf < 2; ++mf)
#pragma unroll
      for (int r = 0; r < 4; ++r) {
        int m = wrow0 + mf * 16 + lhi * 4 + r;
        int grow = bm + m;
        int gg = (grow < NN) ? grow : NN - 1;
        int sw = (m & 7) << 4;
#pragma unroll
        for (int nf = 0; nf < 4; ++nf) {
          int f = mf * 4 + nf;
          int col = wcol0 + nf * 16 + l15;
          float zv = sigm(acc[f][r] + bih[128 + col] + bhh[128 + col]);
          float hoh = bf2f(*(const unsigned short*)(cat + m * 512 + ((256 + 2 * col) ^ sw)));
          float hol = bf2f(hlo[(size_t)gg * 128 + col]);
          hv[f][r] = (1.f - zv) * nn[f][r] + zv * (hoh + hol);
        }
      }
  }

  // ---- stage hi/lo into LDS (reuse cat), then coalesced store ----
  __syncthreads();
#pragma unroll
  for (int mf = 0; mf < 2; ++mf)
#pragma unroll
    for (int r = 0; r < 4; ++r) {
      int m = wrow0 + mf * 16 + lhi * 4 + r;
      int sw = (m & 7) << 4;
#pragma unroll
      for (int nf = 0; nf < 4; ++nf) {
        int f = mf * 4 + nf;
        int col = wcol0 + nf * 16 + l15;
        float v = hv[f][r];
        unsigned short hi = f2bf(v);
        *(unsigned short*)(cat + m * 256 + ((2 * col) ^ sw)) = hi;
        *(unsigned short*)(cat + 16384 + m * 256 + ((2 * col) ^ sw)) = f2bf(v - bf2f(hi));
      }
    }
  __syncthreads();
  for (int idx = tid; idx < 1024; idx += 256) {
    int row = idx >> 4, seg = idx & 15;
    int gr = bm + row;
    if (gr < NN) {
      int so = row * 256 + ((seg * 16) ^ ((row & 7) << 4));
      uint4 vh = *(const uint4*)(cat + so);
      uint4 vl = *(const uint4*)(cat + 16384 + so);
      *(uint4*)((char*)hbf + (size_t)gr * 256 + seg * 16) = vh;
      *(uint4*)((char*)hlo + (size_t)gr * 256 + seg * 16) = vl;
    }
  }
}

// ---------- fp32 GEMM for h0 (B streamed from cache) ----------
template <int KD>
__global__ void __launch_bounds__(256)
gemm_cacheB(const float* __restrict__ X, const int* __restrict__ rowidx,
            const float* __restrict__ B, int ldb, const float* __restrict__ bias,
            float* __restrict__ C, int M) {
  __shared__ float xs[KD * 64];
  constexpr int KC = KD / 4;
  const int tid = threadIdx.x;
  const int bm = blockIdx.x * 64;

  for (int idx = tid; idx < 64 * KC; idx += 256) {
    int m = idx / KC, c = idx - m * KC;
    int gm = bm + m;
    float4 v = make_float4(0.f, 0.f, 0.f, 0.f);
    if (gm < M) {
      int r = rowidx ? rowidx[gm] : gm;
      v = *(const float4*)(X + (size_t)r * KD + 4 * c);
    }
    int k0 = 4 * c;
    xs[(k0 + 0) * 64 + ((((m >> 2) ^ ((k0 + 0) & 15)) << 2) | (m & 3))] = v.x;
    xs[(k0 + 1) * 64 + ((((m >> 2) ^ ((k0 + 1) & 15)) << 2) | (m & 3))] = v.y;
    xs[(k0 + 2) * 64 + ((((m >> 2) ^ ((k0 + 2) & 15)) << 2) | (m & 3))] = v.z;
    xs[(k0 + 3) * 64 + ((((m >> 2) ^ ((k0 + 3) & 15)) << 2) | (m & 3))] = v.w;
  }
  __syncthreads();

  const int tx = tid & 15, ty = tid >> 4;
  float acc[4][8] = {};
#pragma unroll 4
  for (int k = 0; k < KD; ++k) {
    float4 a = *(float4*)(xs + k * 64 + ((ty ^ (k & 15)) << 2));
    float4 b0 = *(const float4*)(B + (size_t)k * ldb + 4 * tx);
    float4 b1 = *(const float4*)(B + (size_t)k * ldb + 64 + 4 * tx);
    float av[4] = {a.x, a.y, a.z, a.w};
    float bv[8] = {b0.x, b0.y, b0.z, b0.w, b1.x, b1.y, b1.z, b1.w};
#pragma unroll
    for (int i = 0; i < 4; ++i)
#pragma unroll
      for (int j = 0; j < 8; ++j) acc[i][j] += av[i] * bv[j];
  }

#pragma unroll
  for (int i = 0; i < 4; ++i) {
    int gm = bm + 4 * ty + i;
    if (gm >= M) continue;
    float4 o0, o1;
    o0.x = acc[i][0] + bias[4 * tx + 0];
    o0.y = acc[i][1] + bias[4 * tx + 1];
    o0.z = acc[i][2] + bias[4 * tx + 2];
    o0.w = acc[i][3] + bias[4 * tx + 3];
    o1.x = acc[i][4] + bias[64 + 4 * tx + 0];
    o1.y = acc[i][5] + bias[64 + 4 * tx + 1];
    o1.z = acc[i][6] + bias[64 + 4 * tx + 2];
    o1.w = acc[i][7] + bias[64 + 4 * tx + 3];
    *(float4*)(C + (size_t)gm * 128 + 4 * tx) = o0;
    *(float4*)(C + (size_t)gm * 128 + 64 + 4 * tx) = o1;
  }
}

// ---------- CSR build keyed by b = et*NN + dst ----------
__global__ void count3_k(const int* __restrict__ dst, const int* __restrict__ et,
                         int* __restrict__ deg3) {
  int e = blockIdx.x * 256 + threadIdx.x;
  if (e < NE) atomicAdd(&deg3[et[e] * NN + dst[e]], 1);
}
__global__ void scan1(const int* __restrict__ deg, int* __restrict__ rowst,
                      int* __restrict__ csum, int L) {
  __shared__ int s[256];
  int base = blockIdx.x * 1024;
  int tid = threadIdx.x;
  int v[4], pre[4];
  int run = 0;
#pragma unroll
  for (int j = 0; j < 4; ++j) {
    int idx = base + tid * 4 + j;
    v[j] = (idx < L) ? deg[idx] : 0;
    pre[j] = run;
    run += v[j];
  }
  s[tid] = run;
  __syncthreads();
  for (int off = 1; off < 256; off <<= 1) {
    int t = (tid >= off) ? s[tid - off] : 0;
    __syncthreads();
    s[tid] += t;
    __syncthreads();
  }
  int excl = (tid == 0) ? 0 : s[tid - 1];
#pragma unroll
  for (int j = 0; j < 4; ++j) {
    int idx = base + tid * 4 + j;
    if (idx < L) rowst[idx] = excl + pre[j];
  }
  if (tid == 255) csum[blockIdx.x] = s[255];
}
__global__ void scan2(int* csum, int nch) {
  if (threadIdx.x == 0 && blockIdx.x == 0) {
    int run = 0;
    for (int i = 0; i < nch; ++i) { int t = csum[i]; csum[i] = run; run += t; }
  }
}
__global__ void scan3(int* rowst, const int* __restrict__ csum, int L) {
  int idx = blockIdx.x * 256 + threadIdx.x;
  if (idx < L) rowst[idx] += csum[idx >> 10];
}
__global__ void set_last(int* rowst) { rowst[3 * NN] = NE; }
__global__ void fill3_k(const int* __restrict__ src, const int* __restrict__ dst,
                        const int* __restrict__ et, const int* __restrict__ rowst3,
                        int* __restrict__ cursor3, int* __restrict__ payload) {
  int e = blockIdx.x * 256 + threadIdx.x;
  if (e >= NE) return;
  int b3 = et[e] * NN + dst[e];
  int pos = rowst3[b3] + atomicAdd(&cursor3[b3], 1);
  payload[pos] = src[e];
}

// ---------- misc ----------
__global__ void transpose_w(const float* __restrict__ W, float* __restrict__ WT,
                            int J, int Kd) {
  int idx = blockIdx.x * 256 + threadIdx.x;
  if (idx >= J * Kd) return;
  int j = idx / Kd, k = idx - j * Kd;
  WT[(size_t)k * J + j] = W[idx];
}

// split fp32 -> hi/lo bf16
__global__ void conv_hilo(const float* __restrict__ s, unsigned short* __restrict__ dhi,
                          unsigned short* __restrict__ dlo, int n4) {
  int i = blockIdx.x * 256 + threadIdx.x;
  if (i >= n4) return;
  float4 v = *(const float4*)(s + 4 * (size_t)i);
  unsigned short h0 = f2bf(v.x), h1 = f2bf(v.y), h2 = f2bf(v.z), h3 = f2bf(v.w);
  uint2 hp, lp;
  hp.x = (unsigned)h0 | ((unsigned)h1 << 16);
  hp.y = (unsigned)h2 | ((unsigned)h3 << 16);
  lp.x = (unsigned)f2bf(v.x - bf2f(h0)) | ((unsigned)f2bf(v.y - bf2f(h1)) << 16);
  lp.y = (unsigned)f2bf(v.z - bf2f(h2)) | ((unsigned)f2bf(v.w - bf2f(h3)) << 16);
  *(uint2*)(dhi + 4 * (size_t)i) = hp;
  *(uint2*)(dlo + 4 * (size_t)i) = lp;
}

// per-node gate scalar AND per-node readout-dot scalar, one feature pass
__global__ void __launch_bounds__(256)
nodeval_k(const unsigned* __restrict__ hhi, const unsigned* __restrict__ hlow,
          const float* __restrict__ h0, const float* __restrict__ Wg,
          const float* __restrict__ bg, const float* __restrict__ Wout,
          float* __restrict__ gate, float* __restrict__ cbuf) {
  int wid = threadIdx.x >> 6, lane = threadIdx.x & 63;
  int n = blockIdx.x * 4 + wid;
  if (n >= NN) return;
  unsigned hi = hhi[(size_t)n * 64 + lane];
  unsigned lo = hlow[(size_t)n * 64 + lane];
  float hx = bf2f(hi & 0xffffu) + bf2f(lo & 0xffffu);
  float hy = bf2f(hi >> 16) + bf2f(lo >> 16);
  float2 h0v = *(const float2*)(h0 + (size_t)n * 128 + 2 * lane);
  float pg = hx * Wg[2 * lane] + hy * Wg[2 * lane + 1] +
             h0v.x * Wg[128 + 2 * lane] + h0v.y * Wg[128 + 2 * lane + 1];
  float pc = hx * Wout[2 * lane] + hy * Wout[2 * lane + 1] +
             h0v.x * Wout[128 + 2 * lane] + h0v.y * Wout[128 + 2 * lane + 1];
  pg = wave_sum(pg);
  pc = wave_sum(pc);
  if (lane == 0) {
    gate[n] = pg + bg[0];
    cbuf[n] = pc;
  }
}

__global__ void bounds_k(const int* __restrict__ gid, int* __restrict__ bound) {
  int g = threadIdx.x;
  if (g > NG) return;
  int lo = 0, hi = NN;
  while (lo < hi) {
    int mid = (lo + hi) >> 1;
    if (gid[mid] < g) lo = mid + 1; else hi = mid;
  }
  bound[g] = lo;
}

// per-graph softmax finalize over scalars only
__global__ void __launch_bounds__(256)
finalize_k(const float* __restrict__ gate, const float* __restrict__ cbuf,
           const int* __restrict__ bound, const float* __restrict__ bout,
           float* __restrict__ out) {
  int g = blockIdx.x;
  int s = bound[g], e = bound[g + 1];
  __shared__ float sred[4], sred2[4];
  __shared__ float sm;
  int tid = threadIdx.x, wid = tid >> 6, lane = tid & 63;
  if (s >= e) { if (tid == 0) out[g] = bout[0]; return; }

  float mx = -3.4e38f;
  for (int i = s + tid; i < e; i += 256) mx = fmaxf(mx, gate[i]);
  mx = wave_max(mx);
  if (lane == 0) sred[wid] = mx;
  __syncthreads();
  if (tid == 0) sm = fmaxf(fmaxf(sred[0], sred[1]), fmaxf(sred[2], sred[3]));
  __syncthreads();
  float m = sm;

  float ss = 0.f, cs = 0.f;
  for (int i = s + tid; i < e; i += 256) {
    float w = __expf(gate[i] - m);
    ss += w;
    cs += w * cbuf[i];
  }
  ss = wave_sum(ss);
  cs = wave_sum(cs);
  if (lane == 0) { sred[wid] = ss; sred2[wid] = cs; }
  __syncthreads();
  if (tid == 0) {
    float S = sred[0] + sred[1] + sred[2] + sred[3];
    float C = sred2[0] + sred2[1] + sred2[2] + sred2[3];
    out[g] = C / S + bout[0];
  }
}

// ---------- host ----------
extern "C" void kernel_launch(void* const* d_in, const int* in_sizes, int n_in,
                              void* d_out, int out_size, void* d_ws, size_t ws_size,
                              hipStream_t stream) {
  (void)in_sizes; (void)n_in; (void)out_size; (void)ws_size;
  const int* type_ids = (const int*)d_in[0];
  const int* src      = (const int*)d_in[1];
  const int* dst      = (const int*)d_in[2];
  const int* etypes   = (const int*)d_in[3];
  const int* gid      = (const int*)d_in[4];
  const float* embed  = (const float*)d_in[5];
  const float* W_red  = (const float*)d_in[6];
  const float* b_red  = (const float*)d_in[7];
  const float* W_msg  = (const float*)d_in[8];
  const float* b_msg  = (const float*)d_in[9];
  const float* W_ih   = (const float*)d_in[10];
  const float* b_ih   = (const float*)d_in[11];
  const float* W_hh   = (const float*)d_in[12];
  const float* b_hh   = (const float*)d_in[13];
  const float* W_gate = (const float*)d_in[14];
  const float* b_gate = (const float*)d_in[15];
  const float* W_out  = (const float*)d_in[16];
  const float* b_out  = (const float*)d_in[17];

  char* p = (char*)d_ws;
  auto take = [&](size_t nb) { char* r = p; p += (nb + 255) & ~(size_t)255; return r; };
  float* h0b           = (float*)take((size_t)NN * 128 * sizeof(float));
  unsigned short* hbf  = (unsigned short*)take((size_t)NN * 128 * 2);
  unsigned short* hlo  = (unsigned short*)take((size_t)NN * 128 * 2);
  unsigned short* abf  = (unsigned short*)take((size_t)NN * 128 * 2);
  unsigned short* Sbuf = (unsigned short*)take((size_t)NN * 384 * 2);
  unsigned short* WcatF = (unsigned short*)take(12 * 8 * 64 * 8 * 2);
  unsigned short* WrzF  = (unsigned short*)take(2 * 8 * 8 * 64 * 8 * 2);
  unsigned short* WihF  = (unsigned short*)take(49152 * 2);
  unsigned short* WhhF  = (unsigned short*)take(49152 * 2);
  float* WredT         = (float*)take(64 * 128 * sizeof(float));
  float* gateb         = (float*)take((size_t)NN * sizeof(float));
  float* cbuf          = (float*)take((size_t)NN * sizeof(float));
  int* deg3    = (int*)take((size_t)2 * 3 * NN * sizeof(int));
  int* cursor3 = deg3 + 3 * NN;
  int* rowst3x = (int*)take(((size_t)3 * NN + 1) * sizeof(int));
  int* payload = (int*)take((size_t)NE * sizeof(int));
  int* csum    = (int*)take(2048);
  int* bound   = (int*)take(512);

  // weight prep
  transpose_w<<<(128 * 64 + 255) / 256, 256, 0, stream>>>(W_red, WredT, 128, 64);
  pack_cat384<<<(12 * 8 * 64 + 255) / 256, 256, 0, stream>>>(W_msg, WcatF);
  pack_rz<<<(2 * 8 * 8 * 64 + 255) / 256, 256, 0, stream>>>(W_ih, W_hh, WrzF);
  pack_fragB<<<24, 256, 0, stream>>>(W_ih, WihF);
  pack_fragB<<<24, 256, 0, stream>>>(W_hh, WhhF);

  // CSR keyed by (etype, dst)
  const int L3 = 3 * NN;
  hipMemsetAsync(deg3, 0, (size_t)2 * L3 * sizeof(int), stream);
  count3_k<<<(NE + 255) / 256, 256, 0, stream>>>(dst, etypes, deg3);
  int nch = (L3 + 1023) / 1024;
  scan1<<<nch, 256, 0, stream>>>(deg3, rowst3x, csum, L3);
  scan2<<<1, 64, 0, stream>>>(csum, nch);
  scan3<<<(L3 + 255) / 256, 256, 0, stream>>>(rowst3x, csum, L3);
  set_last<<<1, 1, 0, stream>>>(rowst3x);
  fill3_k<<<(NE + 255) / 256, 256, 0, stream>>>(src, dst, etypes, rowst3x, cursor3, payload);

  // h0 = embed[type_ids] @ W_red^T + b_red ; h = h0 as hi/lo bf16 pair
  gemm_cacheB<64><<<(NN + 63) / 64, 256, 0, stream>>>(
      embed, type_ids, WredT, 128, b_red, h0b, NN);
  conv_hilo<<<((NN * 128 / 4) + 255) / 256, 256, 0, stream>>>(h0b, hbf, hlo, NN * 128 / 4);

  const int nblk = (NN + 63) / 64;
  const int ngb = (3 * NN + 3) / 4;
  for (int s6 = 0; s6 < 6; ++s6) {
    gather_k<<<ngb, 256, 0, stream>>>((const unsigned*)hbf, rowst3x, payload, Sbuf);
    msg_gemm6<<<nblk, 256, 0, stream>>>(Sbuf, WcatF, b_msg, rowst3x, abf);
    gru5<<<nblk, 256, 0, stream>>>(hbf, hlo, abf, WrzF, WihF, WhhF, b_ih, b_hh);
  }

  nodeval_k<<<(NN + 3) / 4, 256, 0, stream>>>((const unsigned*)hbf, (const unsigned*)hlo,
                                              h0b, W_gate, b_gate, W_out, gateb, cbuf);
  bounds_k<<<1, 128, 0, stream>>>(gid, bound);
  finalize_k<<<NG, 256, 0, stream>>>(gateb, cbuf, bound, b_out, (float*)d_out);
}

// Round 14
// 1468.387 us; speedup vs baseline: 1.1467x; 1.1467x over previous
//
#include <hip/hip_runtime.h>

#define NN 100000
#define NE 1600000
#define NG 64

typedef __attribute__((ext_vector_type(8))) short bf16x8;
typedef __attribute__((ext_vector_type(4))) float f32x4;

__device__ __forceinline__ unsigned short f2bf(float f) {
  unsigned u = __float_as_uint(f);
  unsigned r = u + 0x7FFFu + ((u >> 16) & 1u);
  return (unsigned short)(r >> 16);
}
__device__ __forceinline__ float bf2f(unsigned u16) {
  return __uint_as_float(u16 << 16);
}

__device__ __forceinline__ float wave_sum(float v) {
#pragma unroll
  for (int off = 32; off; off >>= 1) v += __shfl_down(v, off, 64);
  return v;
}
__device__ __forceinline__ float wave_max(float v) {
#pragma unroll
  for (int off = 32; off; off >>= 1) v = fmaxf(v, __shfl_down(v, off, 64));
  return v;
}

__device__ __forceinline__ float sigm(float v) { return 1.f / (1.f + __expf(-v)); }

// ---------------- gather: one wave per (etype,node) task, row-layout S ----------------
__global__ void __launch_bounds__(256)
gather_k(const unsigned* __restrict__ hbf32, const int* __restrict__ rowst,
         const int* __restrict__ payload, unsigned short* __restrict__ S) {
  const int lane = threadIdx.x & 63, wid = threadIdx.x >> 6;
  int task = blockIdx.x * 4 + wid;
  if (task >= 3 * NN) return;
  const int s = rowst[task], e = rowst[task + 1];
  float sx = 0.f, sy = 0.f;
  int i = s;
  for (; i + 4 <= e; i += 4) {
    int p0 = payload[i], p1 = payload[i + 1], p2 = payload[i + 2], p3 = payload[i + 3];
    unsigned v0 = hbf32[(size_t)p0 * 64 + lane];
    unsigned v1 = hbf32[(size_t)p1 * 64 + lane];
    unsigned v2 = hbf32[(size_t)p2 * 64 + lane];
    unsigned v3 = hbf32[(size_t)p3 * 64 + lane];
    sx += bf2f(v0 & 0xffffu) + bf2f(v1 & 0xffffu) + bf2f(v2 & 0xffffu) + bf2f(v3 & 0xffffu);
    sy += bf2f(v0 >> 16) + bf2f(v1 >> 16) + bf2f(v2 >> 16) + bf2f(v3 >> 16);
  }
  const int rem = e - i;
  if (rem == 3) {
    int p0 = payload[i], p1 = payload[i + 1], p2 = payload[i + 2];
    unsigned v0 = hbf32[(size_t)p0 * 64 + lane];
    unsigned v1 = hbf32[(size_t)p1 * 64 + lane];
    unsigned v2 = hbf32[(size_t)p2 * 64 + lane];
    sx += bf2f(v0 & 0xffffu) + bf2f(v1 & 0xffffu) + bf2f(v2 & 0xffffu);
    sy += bf2f(v0 >> 16) + bf2f(v1 >> 16) + bf2f(v2 >> 16);
  } else if (rem == 2) {
    int p0 = payload[i], p1 = payload[i + 1];
    unsigned v0 = hbf32[(size_t)p0 * 64 + lane];
    unsigned v1 = hbf32[(size_t)p1 * 64 + lane];
    sx += bf2f(v0 & 0xffffu) + bf2f(v1 & 0xffffu);
    sy += bf2f(v0 >> 16) + bf2f(v1 >> 16);
  } else if (rem == 1) {
    int p0 = payload[i];
    unsigned v0 = hbf32[(size_t)p0 * 64 + lane];
    sx += bf2f(v0 & 0xffffu);
    sy += bf2f(v0 >> 16);
  }
  const int et = task / NN;
  const int n = task - et * NN;
  unsigned pk = (unsigned)f2bf(sx) | ((unsigned)f2bf(sy) << 16);
  *(unsigned*)(S + (size_t)n * 384 + et * 128 + 2 * lane) = pk;
}

// ---------------- fragment-major packs ----------------
// K=128, 3 gate panels: fidx = ((g*4+ks)*8 + cc)*64 + lane
__global__ void pack_fragB(const float* __restrict__ W, unsigned short* __restrict__ WF) {
  int idx = blockIdx.x * 256 + threadIdx.x;
  if (idx >= 3 * 4 * 8 * 64) return;
  int lane = idx & 63;
  int cc = (idx >> 6) & 7;
  int ks = (idx >> 9) & 3;
  int g = idx >> 11;
  int col = cc * 16 + (lane & 15);
  int k0 = ks * 32 + (lane >> 4) * 8;
  const float* src = W + ((size_t)g * 128 + col) * 128 + k0;
  bf16x8 o;
#pragma unroll
  for (int j = 0; j < 8; ++j) o[j] = (short)f2bf(src[j]);
  *(bf16x8*)(WF + (size_t)idx * 8) = o;
}

// K=256 stacked [Wih;Whh] for gates r(g=0), z(g=1): fidx = ((g*8+ks)*8 + cc)*64 + lane
__global__ void pack_rz(const float* __restrict__ Wih, const float* __restrict__ Whh,
                        unsigned short* __restrict__ WF) {
  int idx = blockIdx.x * 256 + threadIdx.x;
  if (idx >= 2 * 8 * 8 * 64) return;
  int lane = idx & 63;
  int cc = (idx >> 6) & 7;
  int ks = (idx >> 9) & 7;
  int g = idx >> 12;
  int col = cc * 16 + (lane & 15);
  int k0 = ks * 32 + (lane >> 4) * 8;
  int row = g * 128 + col;
  const float* src = (k0 < 128) ? (Wih + (size_t)row * 128 + k0)
                                : (Whh + (size_t)row * 128 + (k0 - 128));
  bf16x8 o;
#pragma unroll
  for (int j = 0; j < 8; ++j) o[j] = (short)f2bf(src[j]);
  *(bf16x8*)(WF + (size_t)idx * 8) = o;
}

// K=384 pack of Wmsg as B[k=et*128+h][col=d] = Wmsg[et,d,h]
__global__ void pack_cat384(const float* __restrict__ Wmsg, unsigned short* __restrict__ WF) {
  int idx = blockIdx.x * 256 + threadIdx.x;
  if (idx >= 12 * 8 * 64) return;
  int lane = idx & 63;
  int cc = (idx >> 6) & 7;
  int ks = idx >> 9;
  int col = cc * 16 + (lane & 15);
  int k0 = ks * 32 + (lane >> 4) * 8;
  int et = k0 >> 7, h0 = k0 & 127;
  const float* src = Wmsg + (size_t)et * 16384 + (size_t)col * 128 + h0;
  bf16x8 o;
#pragma unroll
  for (int j = 0; j < 8; ++j) o[j] = (short)f2bf(src[j]);
  *(bf16x8*)(WF + (size_t)idx * 8) = o;
}

// ---------------- msg GEMM: a = S @ Wcat^T + deg bias (K=384), 32-row tiles ----------------
__global__ void __launch_bounds__(256, 4)
msg_gemm6(const unsigned short* __restrict__ S, const unsigned short* __restrict__ WcatF,
          const float* __restrict__ bmsg, const int* __restrict__ rowst,
          unsigned short* __restrict__ abf) {
  __shared__ char Ss[24576];  // 32 rows x 384 bf16 (768B), swizzled
  const int tid = threadIdx.x, lane = tid & 63, wid = tid >> 6;
  const int l15 = lane & 15, lhi = lane >> 4;
  const int bm = blockIdx.x * 32;
  const int wrow0 = (wid >> 1) * 16, wcol0 = (wid & 1) * 64;

  for (int idx = tid; idx < 1536; idx += 256) {
    int row = idx / 48, o = (idx - row * 48) * 16;
    int gr = bm + row;
    uint4 v = make_uint4(0, 0, 0, 0);
    if (gr < NN) v = *(const uint4*)((const char*)S + (size_t)gr * 768 + o);
    *(uint4*)(Ss + row * 768 + (o ^ ((row & 7) << 4))) = v;
  }
  __syncthreads();

  f32x4 acc[4];
#pragma unroll
  for (int f = 0; f < 4; ++f)
#pragma unroll
    for (int r = 0; r < 4; ++r) acc[f][r] = 0.f;

#pragma unroll
  for (int ks = 0; ks < 12; ++ks) {
    int kb = ks * 64 + lhi * 16;
    int row = wrow0 + l15;
    bf16x8 fS = *(const bf16x8*)(Ss + row * 768 + (kb ^ ((row & 7) << 4)));
#pragma unroll
    for (int nf = 0; nf < 4; ++nf) {
      bf16x8 bw = *(const bf16x8*)(WcatF +
          (((size_t)ks * 8 + (wcol0 >> 4) + nf) * 64 + lane) * 8);
      acc[nf] = __builtin_amdgcn_mfma_f32_16x16x32_bf16(fS, bw, acc[nf], 0, 0, 0);
    }
  }

#pragma unroll
  for (int r = 0; r < 4; ++r) {
    int grow = bm + wrow0 + lhi * 4 + r;
    if (grow >= NN) continue;
    float d0 = (float)(rowst[grow + 1] - rowst[grow]);
    float d1 = (float)(rowst[NN + grow + 1] - rowst[NN + grow]);
    float d2 = (float)(rowst[2 * NN + grow + 1] - rowst[2 * NN + grow]);
#pragma unroll
    for (int nf = 0; nf < 4; ++nf) {
      int col = wcol0 + nf * 16 + l15;
      float v = acc[nf][r] + d0 * bmsg[col] + d1 * bmsg[128 + col] +
                d2 * bmsg[256 + col];
      abf[(size_t)grow * 128 + col] = f2bf(v);
    }
  }
}

// ---------------- GRU v6: 32-row tiles, hi/lo h, r->n->z, K=256 concat for r,z ----------------
__global__ void __launch_bounds__(256, 4)
gru6(unsigned short* __restrict__ hbf, unsigned short* __restrict__ hlo,
     const unsigned short* __restrict__ abf, const unsigned short* __restrict__ WrzF,
     const unsigned short* __restrict__ WihF, const unsigned short* __restrict__ WhhF,
     const float* __restrict__ bih, const float* __restrict__ bhh) {
  __shared__ char cat[32 * 512];  // per row: [a 256B | h 256B], swizzled within row
  const int tid = threadIdx.x, lane = tid & 63, wid = tid >> 6;
  const int l15 = lane & 15, lhi = lane >> 4;
  const int bm = blockIdx.x * 32;
  const int wrow0 = (wid >> 1) * 16, wcol0 = (wid & 1) * 64;

  for (int idx = tid; idx < 1024; idx += 256) {
    int row = idx >> 5, seg = idx & 31;
    int gr = bm + row;
    uint4 v = make_uint4(0, 0, 0, 0);
    if (gr < NN) {
      if (seg < 16)
        v = *(const uint4*)((const char*)abf + (size_t)gr * 256 + seg * 16);
      else
        v = *(const uint4*)((const char*)hbf + (size_t)gr * 256 + (seg - 16) * 16);
    }
    int o = seg * 16;
    *(uint4*)(cat + row * 512 + (o ^ ((row & 7) << 4))) = v;
  }
  __syncthreads();

  // ---- gate r: K=256 concat ----
  f32x4 rr[4];
  {
    f32x4 acc[4];
#pragma unroll
    for (int f = 0; f < 4; ++f)
#pragma unroll
      for (int r = 0; r < 4; ++r) acc[f][r] = 0.f;
#pragma unroll
    for (int ks = 0; ks < 8; ++ks) {
      int kb = ks * 64 + lhi * 16;
      int row = wrow0 + l15;
      bf16x8 fA = *(const bf16x8*)(cat + row * 512 + (kb ^ ((row & 7) << 4)));
#pragma unroll
      for (int nf = 0; nf < 4; ++nf) {
        bf16x8 bw = *(const bf16x8*)(WrzF +
            (((size_t)ks * 8 + (wcol0 >> 4) + nf) * 64 + lane) * 8);
        acc[nf] = __builtin_amdgcn_mfma_f32_16x16x32_bf16(fA, bw, acc[nf], 0, 0, 0);
      }
    }
#pragma unroll
    for (int f = 0; f < 4; ++f) {
      int col = wcol0 + f * 16 + l15;
      float b = bih[col] + bhh[col];
#pragma unroll
      for (int r = 0; r < 4; ++r) rr[f][r] = sigm(acc[f][r] + b);
    }
  }

  // ---- gate n: separate acc_i (a half) and acc_h (h half) ----
  f32x4 nn[4];
  {
    f32x4 acc_i[4], acc_h[4];
#pragma unroll
    for (int f = 0; f < 4; ++f)
#pragma unroll
      for (int r = 0; r < 4; ++r) { acc_i[f][r] = 0.f; acc_h[f][r] = 0.f; }
#pragma unroll
    for (int ks = 0; ks < 4; ++ks) {
      int kb = ks * 64 + lhi * 16;
      int row = wrow0 + l15;
      int sw = (row & 7) << 4;
      bf16x8 fa = *(const bf16x8*)(cat + row * 512 + (kb ^ sw));
      bf16x8 fh = *(const bf16x8*)(cat + row * 512 + ((256 + kb) ^ sw));
#pragma unroll
      for (int nf = 0; nf < 4; ++nf) {
        size_t fidx = (((size_t)(2 * 4 + ks) * 8 + (wcol0 >> 4) + nf) * 64 + lane) * 8;
        bf16x8 bi = *(const bf16x8*)(WihF + fidx);
        bf16x8 bh = *(const bf16x8*)(WhhF + fidx);
        acc_i[nf] = __builtin_amdgcn_mfma_f32_16x16x32_bf16(fa, bi, acc_i[nf], 0, 0, 0);
        acc_h[nf] = __builtin_amdgcn_mfma_f32_16x16x32_bf16(fh, bh, acc_h[nf], 0, 0, 0);
      }
    }
#pragma unroll
    for (int f = 0; f < 4; ++f) {
      int col = wcol0 + f * 16 + l15;
      float bi = bih[256 + col], bh = bhh[256 + col];
#pragma unroll
      for (int r = 0; r < 4; ++r) {
        float x = acc_i[f][r] + bi + rr[f][r] * (acc_h[f][r] + bh);
        float e = __expf(-2.f * x);
        nn[f][r] = (1.f - e) / (1.f + e);
      }
    }
  }

  // ---- gate z: K=256 concat, then blend + store hi/lo ----
  {
    f32x4 acc[4];
#pragma unroll
    for (int f = 0; f < 4; ++f)
#pragma unroll
      for (int r = 0; r < 4; ++r) acc[f][r] = 0.f;
#pragma unroll
    for (int ks = 0; ks < 8; ++ks) {
      int kb = ks * 64 + lhi * 16;
      int row = wrow0 + l15;
      bf16x8 fA = *(const bf16x8*)(cat + row * 512 + (kb ^ ((row & 7) << 4)));
#pragma unroll
      for (int nf = 0; nf < 4; ++nf) {
        bf16x8 bw = *(const bf16x8*)(WrzF +
            (((size_t)(8 + ks) * 8 + (wcol0 >> 4) + nf) * 64 + lane) * 8);
        acc[nf] = __builtin_amdgcn_mfma_f32_16x16x32_bf16(fA, bw, acc[nf], 0, 0, 0);
      }
    }
#pragma unroll
    for (int r = 0; r < 4; ++r) {
      int m = wrow0 + lhi * 4 + r;
      int grow = bm + m;
      if (grow >= NN) continue;
      int sw = (m & 7) << 4;
#pragma unroll
      for (int nf = 0; nf < 4; ++nf) {
        int col = wcol0 + nf * 16 + l15;
        float zv = sigm(acc[nf][r] + bih[128 + col] + bhh[128 + col]);
        float hoh = bf2f(*(const unsigned short*)(cat + m * 512 + ((256 + 2 * col) ^ sw)));
        float hol = bf2f(hlo[(size_t)grow * 128 + col]);
        float hv = (1.f - zv) * nn[nf][r] + zv * (hoh + hol);
        unsigned short hi = f2bf(hv);
        hbf[(size_t)grow * 128 + col] = hi;
        hlo[(size_t)grow * 128 + col] = f2bf(hv - bf2f(hi));
      }
    }
  }
}

// ---------- fp32 GEMM for h0 (B streamed from cache) ----------
template <int KD>
__global__ void __launch_bounds__(256)
gemm_cacheB(const float* __restrict__ X, const int* __restrict__ rowidx,
            const float* __restrict__ B, int ldb, const float* __restrict__ bias,
            float* __restrict__ C, int M) {
  __shared__ float xs[KD * 64];
  constexpr int KC = KD / 4;
  const int tid = threadIdx.x;
  const int bm = blockIdx.x * 64;

  for (int idx = tid; idx < 64 * KC; idx += 256) {
    int m = idx / KC, c = idx - m * KC;
    int gm = bm + m;
    float4 v = make_float4(0.f, 0.f, 0.f, 0.f);
    if (gm < M) {
      int r = rowidx ? rowidx[gm] : gm;
      v = *(const float4*)(X + (size_t)r * KD + 4 * c);
    }
    int k0 = 4 * c;
    xs[(k0 + 0) * 64 + ((((m >> 2) ^ ((k0 + 0) & 15)) << 2) | (m & 3))] = v.x;
    xs[(k0 + 1) * 64 + ((((m >> 2) ^ ((k0 + 1) & 15)) << 2) | (m & 3))] = v.y;
    xs[(k0 + 2) * 64 + ((((m >> 2) ^ ((k0 + 2) & 15)) << 2) | (m & 3))] = v.z;
    xs[(k0 + 3) * 64 + ((((m >> 2) ^ ((k0 + 3) & 15)) << 2) | (m & 3))] = v.w;
  }
  __syncthreads();

  const int tx = tid & 15, ty = tid >> 4;
  float acc[4][8] = {};
#pragma unroll 4
  for (int k = 0; k < KD; ++k) {
    float4 a = *(float4*)(xs + k * 64 + ((ty ^ (k & 15)) << 2));
    float4 b0 = *(const float4*)(B + (size_t)k * ldb + 4 * tx);
    float4 b1 = *(const float4*)(B + (size_t)k * ldb + 64 + 4 * tx);
    float av[4] = {a.x, a.y, a.z, a.w};
    float bv[8] = {b0.x, b0.y, b0.z, b0.w, b1.x, b1.y, b1.z, b1.w};
#pragma unroll
    for (int i = 0; i < 4; ++i)
#pragma unroll
      for (int j = 0; j < 8; ++j) acc[i][j] += av[i] * bv[j];
  }

#pragma unroll
  for (int i = 0; i < 4; ++i) {
    int gm = bm + 4 * ty + i;
    if (gm >= M) continue;
    float4 o0, o1;
    o0.x = acc[i][0] + bias[4 * tx + 0];
    o0.y = acc[i][1] + bias[4 * tx + 1];
    o0.z = acc[i][2] + bias[4 * tx + 2];
    o0.w = acc[i][3] + bias[4 * tx + 3];
    o1.x = acc[i][4] + bias[64 + 4 * tx + 0];
    o1.y = acc[i][5] + bias[64 + 4 * tx + 1];
    o1.z = acc[i][6] + bias[64 + 4 * tx + 2];
    o1.w = acc[i][7] + bias[64 + 4 * tx + 3];
    *(float4*)(C + (size_t)gm * 128 + 4 * tx) = o0;
    *(float4*)(C + (size_t)gm * 128 + 64 + 4 * tx) = o1;
  }
}

// ---------- CSR build keyed by b = et*NN + dst ----------
__global__ void count3_k(const int* __restrict__ dst, const int* __restrict__ et,
                         int* __restrict__ deg3) {
  int e = blockIdx.x * 256 + threadIdx.x;
  if (e < NE) atomicAdd(&deg3[et[e] * NN + dst[e]], 1);
}
__global__ void scan1(const int* __restrict__ deg, int* __restrict__ rowst,
                      int* __restrict__ csum, int L) {
  __shared__ int s[256];
  int base = blockIdx.x * 1024;
  int tid = threadIdx.x;
  int v[4], pre[4];
  int run = 0;
#pragma unroll
  for (int j = 0; j < 4; ++j) {
    int idx = base + tid * 4 + j;
    v[j] = (idx < L) ? deg[idx] : 0;
    pre[j] = run;
    run += v[j];
  }
  s[tid] = run;
  __syncthreads();
  for (int off = 1; off < 256; off <<= 1) {
    int t = (tid >= off) ? s[tid - off] : 0;
    __syncthreads();
    s[tid] += t;
    __syncthreads();
  }
  int excl = (tid == 0) ? 0 : s[tid - 1];
#pragma unroll
  for (int j = 0; j < 4; ++j) {
    int idx = base + tid * 4 + j;
    if (idx < L) rowst[idx] = excl + pre[j];
  }
  if (tid == 255) csum[blockIdx.x] = s[255];
}
__global__ void scan2(int* csum, int nch) {
  if (threadIdx.x == 0 && blockIdx.x == 0) {
    int run = 0;
    for (int i = 0; i < nch; ++i) { int t = csum[i]; csum[i] = run; run += t; }
  }
}
__global__ void scan3(int* rowst, const int* __restrict__ csum, int L) {
  int idx = blockIdx.x * 256 + threadIdx.x;
  if (idx < L) rowst[idx] += csum[idx >> 10];
}
__global__ void set_last(int* rowst) { rowst[3 * NN] = NE; }
__global__ void fill3_k(const int* __restrict__ src, const int* __restrict__ dst,
                        const int* __restrict__ et, const int* __restrict__ rowst3,
                        int* __restrict__ cursor3, int* __restrict__ payload) {
  int e = blockIdx.x * 256 + threadIdx.x;
  if (e >= NE) return;
  int b3 = et[e] * NN + dst[e];
  int pos = rowst3[b3] + atomicAdd(&cursor3[b3], 1);
  payload[pos] = src[e];
}

// ---------- misc ----------
__global__ void transpose_w(const float* __restrict__ W, float* __restrict__ WT,
                            int J, int Kd) {
  int idx = blockIdx.x * 256 + threadIdx.x;
  if (idx >= J * Kd) return;
  int j = idx / Kd, k = idx - j * Kd;
  WT[(size_t)k * J + j] = W[idx];
}

// split fp32 -> hi/lo bf16
__global__ void conv_hilo(const float* __restrict__ s, unsigned short* __restrict__ dhi,
                          unsigned short* __restrict__ dlo, int n4) {
  int i = blockIdx.x * 256 + threadIdx.x;
  if (i >= n4) return;
  float4 v = *(const float4*)(s + 4 * (size_t)i);
  unsigned short h0 = f2bf(v.x), h1 = f2bf(v.y), h2 = f2bf(v.z), h3 = f2bf(v.w);
  uint2 hp, lp;
  hp.x = (unsigned)h0 | ((unsigned)h1 << 16);
  hp.y = (unsigned)h2 | ((unsigned)h3 << 16);
  lp.x = (unsigned)f2bf(v.x - bf2f(h0)) | ((unsigned)f2bf(v.y - bf2f(h1)) << 16);
  lp.y = (unsigned)f2bf(v.z - bf2f(h2)) | ((unsigned)f2bf(v.w - bf2f(h3)) << 16);
  *(uint2*)(dhi + 4 * (size_t)i) = hp;
  *(uint2*)(dlo + 4 * (size_t)i) = lp;
}

// per-node gate scalar AND per-node readout-dot scalar, one feature pass
__global__ void __launch_bounds__(256)
nodeval_k(const unsigned* __restrict__ hhi, const unsigned* __restrict__ hlow,
          const float* __restrict__ h0, const float* __restrict__ Wg,
          const float* __restrict__ bg, const float* __restrict__ Wout,
          float* __restrict__ gate, float* __restrict__ cbuf) {
  int wid = threadIdx.x >> 6, lane = threadIdx.x & 63;
  int n = blockIdx.x * 4 + wid;
  if (n >= NN) return;
  unsigned hi = hhi[(size_t)n * 64 + lane];
  unsigned lo = hlow[(size_t)n * 64 + lane];
  float hx = bf2f(hi & 0xffffu) + bf2f(lo & 0xffffu);
  float hy = bf2f(hi >> 16) + bf2f(lo >> 16);
  float2 h0v = *(const float2*)(h0 + (size_t)n * 128 + 2 * lane);
  float pg = hx * Wg[2 * lane] + hy * Wg[2 * lane + 1] +
             h0v.x * Wg[128 + 2 * lane] + h0v.y * Wg[128 + 2 * lane + 1];
  float pc = hx * Wout[2 * lane] + hy * Wout[2 * lane + 1] +
             h0v.x * Wout[128 + 2 * lane] + h0v.y * Wout[128 + 2 * lane + 1];
  pg = wave_sum(pg);
  pc = wave_sum(pc);
  if (lane == 0) {
    gate[n] = pg + bg[0];
    cbuf[n] = pc;
  }
}

__global__ void bounds_k(const int* __restrict__ gid, int* __restrict__ bound) {
  int g = threadIdx.x;
  if (g > NG) return;
  int lo = 0, hi = NN;
  while (lo < hi) {
    int mid = (lo + hi) >> 1;
    if (gid[mid] < g) lo = mid + 1; else hi = mid;
  }
  bound[g] = lo;
}

// per-graph softmax finalize over scalars only
__global__ void __launch_bounds__(256)
finalize_k(const float* __restrict__ gate, const float* __restrict__ cbuf,
           const int* __restrict__ bound, const float* __restrict__ bout,
           float* __restrict__ out) {
  int g = blockIdx.x;
  int s = bound[g], e = bound[g + 1];
  __shared__ float sred[4], sred2[4];
  __shared__ float sm;
  int tid = threadIdx.x, wid = tid >> 6, lane = tid & 63;
  if (s >= e) { if (tid == 0) out[g] = bout[0]; return; }

  float mx = -3.4e38f;
  for (int i = s + tid; i < e; i += 256) mx = fmaxf(mx, gate[i]);
  mx = wave_max(mx);
  if (lane == 0) sred[wid] = mx;
  __syncthreads();
  if (tid == 0) sm = fmaxf(fmaxf(sred[0], sred[1]), fmaxf(sred[2], sred[3]));
  __syncthreads();
  float m = sm;

  float ss = 0.f, cs = 0.f;
  for (int i = s + tid; i < e; i += 256) {
    float w = __expf(gate[i] - m);
    ss += w;
    cs += w * cbuf[i];
  }
  ss = wave_sum(ss);
  cs = wave_sum(cs);
  if (lane == 0) { sred[wid] = ss; sred2[wid] = cs; }
  __syncthreads();
  if (tid == 0) {
    float S = sred[0] + sred[1] + sred[2] + sred[3];
    float C = sred2[0] + sred2[1] + sred2[2] + sred2[3];
    out[g] = C / S + bout[0];
  }
}

// ---------- host ----------
extern "C" void kernel_launch(void* const* d_in, const int* in_sizes, int n_in,
                              void* d_out, int out_size, void* d_ws, size_t ws_size,
                              hipStream_t stream) {
  (void)in_sizes; (void)n_in; (void)out_size; (void)ws_size;
  const int* type_ids = (const int*)d_in[0];
  const int* src      = (const int*)d_in[1];
  const int* dst      = (const int*)d_in[2];
  const int* etypes   = (const int*)d_in[3];
  const int* gid      = (const int*)d_in[4];
  const float* embed  = (const float*)d_in[5];
  const float* W_red  = (const float*)d_in[6];
  const float* b_red  = (const float*)d_in[7];
  const float* W_msg  = (const float*)d_in[8];
  const float* b_msg  = (const float*)d_in[9];
  const float* W_ih   = (const float*)d_in[10];
  const float* b_ih   = (const float*)d_in[11];
  const float* W_hh   = (const float*)d_in[12];
  const float* b_hh   = (const float*)d_in[13];
  const float* W_gate = (const float*)d_in[14];
  const float* b_gate = (const float*)d_in[15];
  const float* W_out  = (const float*)d_in[16];
  const float* b_out  = (const float*)d_in[17];

  char* p = (char*)d_ws;
  auto take = [&](size_t nb) { char* r = p; p += (nb + 255) & ~(size_t)255; return r; };
  float* h0b           = (float*)take((size_t)NN * 128 * sizeof(float));
  unsigned short* hbf  = (unsigned short*)take((size_t)NN * 128 * 2);
  unsigned short* hlo  = (unsigned short*)take((size_t)NN * 128 * 2);
  unsigned short* abf  = (unsigned short*)take((size_t)NN * 128 * 2);
  unsigned short* Sbuf = (unsigned short*)take((size_t)NN * 384 * 2);
  unsigned short* WcatF = (unsigned short*)take(12 * 8 * 64 * 8 * 2);
  unsigned short* WrzF  = (unsigned short*)take(2 * 8 * 8 * 64 * 8 * 2);
  unsigned short* WihF  = (unsigned short*)take(49152 * 2);
  unsigned short* WhhF  = (unsigned short*)take(49152 * 2);
  float* WredT         = (float*)take(64 * 128 * sizeof(float));
  float* gateb         = (float*)take((size_t)NN * sizeof(float));
  float* cbuf          = (float*)take((size_t)NN * sizeof(float));
  int* deg3    = (int*)take((size_t)2 * 3 * NN * sizeof(int));
  int* cursor3 = deg3 + 3 * NN;
  int* rowst3x = (int*)take(((size_t)3 * NN + 1) * sizeof(int));
  int* payload = (int*)take((size_t)NE * sizeof(int));
  int* csum    = (int*)take(2048);
  int* bound   = (int*)take(512);

  // weight prep
  transpose_w<<<(128 * 64 + 255) / 256, 256, 0, stream>>>(W_red, WredT, 128, 64);
  pack_cat384<<<(12 * 8 * 64 + 255) / 256, 256, 0, stream>>>(W_msg, WcatF);
  pack_rz<<<(2 * 8 * 8 * 64 + 255) / 256, 256, 0, stream>>>(W_ih, W_hh, WrzF);
  pack_fragB<<<24, 256, 0, stream>>>(W_ih, WihF);
  pack_fragB<<<24, 256, 0, stream>>>(W_hh, WhhF);

  // CSR keyed by (etype, dst)
  const int L3 = 3 * NN;
  hipMemsetAsync(deg3, 0, (size_t)2 * L3 * sizeof(int), stream);
  count3_k<<<(NE + 255) / 256, 256, 0, stream>>>(dst, etypes, deg3);
  int nch = (L3 + 1023) / 1024;
  scan1<<<nch, 256, 0, stream>>>(deg3, rowst3x, csum, L3);
  scan2<<<1, 64, 0, stream>>>(csum, nch);
  scan3<<<(L3 + 255) / 256, 256, 0, stream>>>(rowst3x, csum, L3);
  set_last<<<1, 1, 0, stream>>>(rowst3x);
  fill3_k<<<(NE + 255) / 256, 256, 0, stream>>>(src, dst, etypes, rowst3x, cursor3, payload);

  // h0 = embed[type_ids] @ W_red^T + b_red ; h = h0 as hi/lo bf16 pair
  gemm_cacheB<64><<<(NN + 63) / 64, 256, 0, stream>>>(
      embed, type_ids, WredT, 128, b_red, h0b, NN);
  conv_hilo<<<((NN * 128 / 4) + 255) / 256, 256, 0, stream>>>(h0b, hbf, hlo, NN * 128 / 4);

  const int nblk32 = (NN + 31) / 32;
  const int ngb = (3 * NN + 3) / 4;
  for (int s6 = 0; s6 < 6; ++s6) {
    gather_k<<<ngb, 256, 0, stream>>>((const unsigned*)hbf, rowst3x, payload, Sbuf);
    msg_gemm6<<<nblk32, 256, 0, stream>>>(Sbuf, WcatF, b_msg, rowst3x, abf);
    gru6<<<nblk32, 256, 0, stream>>>(hbf, hlo, abf, WrzF, WihF, WhhF, b_ih, b_hh);
  }

  nodeval_k<<<(NN + 3) / 4, 256, 0, stream>>>((const unsigned*)hbf, (const unsigned*)hlo,
                                              h0b, W_gate, b_gate, W_out, gateb, cbuf);
  bounds_k<<<1, 128, 0, stream>>>(gid, bound);
  finalize_k<<<NG, 256, 0, stream>>>(gateb, cbuf, bound, b_out, (float*)d_out);
}